// Round 8
// baseline (8954.731 us; speedup 1.0000x reference)
//
#include <hip/hip_runtime.h>
#include <stdint.h>

// ---------------------------------------------------------------------------
// ST-LSTM on MI355X.
//  K0 k_prep   : W_catT (2048x1536 bf16, T+XOR-swizzled), Wh_rearr (2048x512
//                bf16, col-reordered, linear), h buf0=0 (tag0 valid),
//                buf1=1 (tag1, invalid for t=1).
//  K1 k_gather : A_cat (16384x1536 bf16, swizzled) = [x | q/3600 | sp/1000].
//  K2 k_gemm   : G (T,B,4H) bf16 = A_cat @ W_cat + bi.
//  K3 k_recur  : 64 active roles from 128 blocks (bid%8<4): r=bid%8, c=bid>>3.
//                ROLE-SPLIT WAVES: waves 0-6 poll the 16 producer slices
//                (tagged f32, parity bit0; sc0 loads whose vmcnt(0) covers
//                ONLY L2-class ops), cvt each slice to MFMA A-fragment layout
//                in LDS, release via monotonic LDS flag; all 8 waves consume
//                slices as they arrive (skew-absorbing). Wave 7 = store wave:
//                agent mirrors (fallback liveness, 1-step lag), outH,
//                last_h/c, and G staging to LDS - all HBM/IC acks land off
//                the poll path. Publish = plain store (same-XCD L2,
//                R4-R6-verified); sticky bounded fallback to agent loads.
//
// ws layout (bytes), total need = 126,091,264 (~120.2 MiB):
#define A_CAT_OFF  0ull                  // 16384*3072
#define WCT_OFF    50331648ull           // 2048*3072
#define WHR_OFF    56623104ull           // 2048*1024 (linear)
#define G_OFF      58720256ull           // 16384*2048*2
#define HBUF_OFF   125829120ull          // 2 bufs x 64 batches x 512 f32 (tagged)
#define WS_NEED    126091264ull

typedef short bf16x8 __attribute__((ext_vector_type(8)));
typedef float f32x4  __attribute__((ext_vector_type(4)));

__device__ __forceinline__ unsigned short f2bf(float f) {
  union { float f; uint32_t u; } v; v.f = f;
  uint32_t u = v.u;
  u += 0x7FFFu + ((u >> 16) & 1u);   // RNE
  return (unsigned short)(u >> 16);
}
__device__ __forceinline__ float bf2f(unsigned short h) {
  union { uint32_t u; float f; } v; v.u = ((uint32_t)h) << 16;
  return v.f;
}
__device__ __forceinline__ float u2f(uint32_t u) {
  union { uint32_t u; float f; } v; v.u = u; return v.f;
}
__device__ __forceinline__ uint32_t f2u(float f) {
  union { float f; uint32_t u; } v; v.f = f; return v.u;
}
__device__ __forceinline__ float fsigmoid(float x) { return 1.0f / (1.0f + __expf(-x)); }
__device__ __forceinline__ float ftanh(float x) {
  float e = __expf(2.0f * x);
  return 1.0f - 2.0f / (e + 1.0f);
}
__device__ __forceinline__ uint4 pack8(const unsigned short* v) {
  uint4 r;
  r.x = (uint32_t)v[0] | ((uint32_t)v[1] << 16);
  r.y = (uint32_t)v[2] | ((uint32_t)v[3] << 16);
  r.z = (uint32_t)v[4] | ((uint32_t)v[5] << 16);
  r.w = (uint32_t)v[6] | ((uint32_t)v[7] << 16);
  return r;
}
__device__ __forceinline__ uint32_t pkbf(uint64_t y) {
  return (uint32_t)f2bf(u2f((uint32_t)y)) |
         ((uint32_t)f2bf(u2f((uint32_t)(y >> 32))) << 16);
}

#define GLOAD_LDS16(GP, LP)                                                   \
  __builtin_amdgcn_global_load_lds(                                          \
      (const __attribute__((address_space(1))) uint32_t*)(GP),               \
      (__attribute__((address_space(3))) uint32_t*)(LP), 16, 0, 0)

// LDS-only barrier: no vmcnt drain (keeps IC/HBM acks off the barrier path)
#define BAR_LDS()                                                             \
  do {                                                                        \
    asm volatile("s_waitcnt lgkmcnt(0)" ::: "memory");                        \
    __builtin_amdgcn_sched_barrier(0);                                        \
    __builtin_amdgcn_s_barrier();                                             \
  } while (0)

// ---------------------------------------------------------------------- K0
__global__ __launch_bounds__(256) void k_prep(
    const float* __restrict__ Wi, const float* __restrict__ Wt,
    const float* __restrict__ Ws, const float* __restrict__ Wh,
    uint8_t* ws) {
  int id = blockIdx.x * 256 + threadIdx.x;
  if (id < 393216) {                       // W_catT: 2048 cols x 192 k-chunks
    int n  = id & 2047;
    int k0 = (id >> 11) << 3;
    unsigned short v[8];
#pragma unroll
    for (int j = 0; j < 8; ++j) {
      int k = k0 + j;
      float x;
      if (k < 512)       x = Wi[k * 2048 + n];
      else if (k < 1024) x = (n < 1536) ? Wt[(k - 512) * 1536 + n] : 0.0f;
      else               x = (n < 1536) ? Ws[(k - 1024) * 1536 + n] : 0.0f;
      v[j] = f2bf(x);
    }
    size_t off = WCT_OFF + (size_t)n * 3072 +
                 (size_t)(((uint32_t)k0 * 2u) ^ (((uint32_t)n & 7u) << 4));
    *(uint4*)(ws + off) = pack8(v);
  } else if (id < 524288) {                // Wh_rearr: LINEAR (reg-consumed)
    int id2 = id - 393216;
    int cc  = id2 & 2047;
    int k0  = (id2 >> 11) << 3;
    int col = ((cc >> 5) & 3) * 512 + (cc >> 7) * 32 + (cc & 31);
    unsigned short v[8];
#pragma unroll
    for (int j = 0; j < 8; ++j) v[j] = f2bf(Wh[(size_t)(k0 + j) * 2048 + col]);
    *(uint4*)(ws + WHR_OFF + (size_t)cc * 1024 + (size_t)k0 * 2) = pack8(v);
  } else if (id < 532480) {                // buf0 = h_0 = +0.0f (tag 0, valid)
    uint4 z; z.x = z.y = z.z = z.w = 0u;
    *(uint4*)(ws + HBUF_OFF + (size_t)(id - 524288) * 16) = z;
  } else if (id < 540672) {                // buf1 = tag 1 (invalid for t=1)
    uint4 z; z.x = z.y = z.z = z.w = 1u;
    *(uint4*)(ws + HBUF_OFF + 131072ull + (size_t)(id - 532480) * 16) = z;
  }
}

// ---------------------------------------------------------------------- K1
__global__ __launch_bounds__(192) void k_gather(
    const int* __restrict__ loc, const int* __restrict__ tdu,
    const int* __restrict__ tdl, const int* __restrict__ sdu,
    const int* __restrict__ sdl,
    const float* __restrict__ loc_emb, const float* __restrict__ tup,
    const float* __restrict__ tlo, const float* __restrict__ sup,
    const float* __restrict__ slo, uint8_t* ws) {
  int m  = blockIdx.x;        // row = b*256 + t
  int t  = m & 255;
  int k0 = threadIdx.x << 3;  // 192 chunks of 8
  float vals[8];
  if (k0 < 512) {
    const float* s = loc_emb + (size_t)loc[m] * 512 + k0;
#pragma unroll
    for (int j = 0; j < 8; ++j) vals[j] = s[j];
  } else if (k0 < 1024) {
    int e = k0 - 512;
    const float* a = tup + (size_t)tdu[m] * 512 + e;
    const float* b = tlo + (size_t)tdl[m] * 512 + e;
    float sc = (t > 0) ? (1.0f / 3600.0f) : 0.0f;
#pragma unroll
    for (int j = 0; j < 8; ++j) vals[j] = (a[j] + b[j]) * sc;
  } else {
    int e = k0 - 1024;
    const float* a = sup + (size_t)sdu[m] * 512 + e;
    const float* b = slo + (size_t)sdl[m] * 512 + e;
    float sc = (t > 0) ? (1.0f / 1000.0f) : 0.0f;
#pragma unroll
    for (int j = 0; j < 8; ++j) vals[j] = (a[j] + b[j]) * sc;
  }
  unsigned short v[8];
#pragma unroll
  for (int j = 0; j < 8; ++j) v[j] = f2bf(vals[j]);
  size_t off = A_CAT_OFF + (size_t)m * 3072 +
               (size_t)(((uint32_t)k0 * 2u) ^ (((uint32_t)m & 7u) << 4));
  *(uint4*)(ws + off) = pack8(v);
}

// ---------------------------------------------------------------------- K2
__global__ __launch_bounds__(256) void k_gemm(uint8_t* ws,
                                              const float* __restrict__ bi) {
  __shared__ uint8_t A_lds[16384];   // 128 rows x 64 k bf16 (swizzled content)
  __shared__ uint8_t B_lds[16384];   // 128 cols x 64 k bf16
  const uint8_t* Acat = ws + A_CAT_OFF;
  const uint8_t* Wct  = ws + WCT_OFF;
  uint8_t* Gp = ws + G_OFF;
  int tid = threadIdx.x;
  int lane = tid & 63, wave = tid >> 6;
  int wm = wave >> 1, wn = wave & 1;
  int tile_m = blockIdx.x >> 4, tile_n = blockIdx.x & 15;

  f32x4 acc[4][4];
#pragma unroll
  for (int m = 0; m < 4; ++m)
#pragma unroll
    for (int n = 0; n < 4; ++n) acc[m][n] = f32x4{0.f, 0.f, 0.f, 0.f};

  for (int kb = 0; kb < 1536; kb += 64) {
#pragma unroll
    for (int i = 0; i < 4; ++i) {
      int lidx = i * 256 + tid;
      int row = lidx >> 3, ch = lidx & 7;
      GLOAD_LDS16(Acat + (size_t)(tile_m * 128 + row) * 3072 + kb * 2 + ch * 16,
                  A_lds + (i * 256 + wave * 64) * 16);
    }
#pragma unroll
    for (int i = 0; i < 4; ++i) {
      int lidx = i * 256 + tid;
      int row = lidx >> 3, ch = lidx & 7;
      GLOAD_LDS16(Wct + (size_t)(tile_n * 128 + row) * 3072 + kb * 2 + ch * 16,
                  B_lds + (i * 256 + wave * 64) * 16);
    }
    __syncthreads();
#pragma unroll
    for (int kk = 0; kk < 2; ++kk) {
      int koff = kk * 64 + ((lane >> 4) << 4);
      bf16x8 af[4], bfr[4];
#pragma unroll
      for (int m = 0; m < 4; ++m) {
        int row = wm * 64 + m * 16 + (lane & 15);
        af[m] = *(const bf16x8*)(A_lds + row * 128 + (koff ^ ((row & 7) << 4)));
      }
#pragma unroll
      for (int n = 0; n < 4; ++n) {
        int row = wn * 64 + n * 16 + (lane & 15);
        bfr[n] = *(const bf16x8*)(B_lds + row * 128 + (koff ^ ((row & 7) << 4)));
      }
#pragma unroll
      for (int m = 0; m < 4; ++m)
#pragma unroll
        for (int n = 0; n < 4; ++n)
          acc[m][n] = __builtin_amdgcn_mfma_f32_16x16x32_bf16(af[m], bfr[n],
                                                              acc[m][n], 0, 0, 0);
    }
    __syncthreads();
  }
  // epilogue: + bias, bf16, scatter to G laid out (T, B, 4H)
  int lr = lane >> 4, lc = lane & 15;
#pragma unroll
  for (int n = 0; n < 4; ++n) {
    int gcol = tile_n * 128 + wn * 64 + n * 16 + lc;
    float bv = bi[gcol];
#pragma unroll
    for (int m = 0; m < 4; ++m) {
      int growb = tile_m * 128 + wm * 64 + m * 16 + lr * 4;
#pragma unroll
      for (int q = 0; q < 4; ++q) {
        int grow = growb + q;                      // = b*256 + t
        float v = acc[m][n][q] + bv;
        size_t gi = ((size_t)(grow & 255) * 64 + (size_t)(grow >> 8)) * 2048 + gcol;
        *(unsigned short*)(Gp + gi * 2) = f2bf(v);
      }
    }
  }
}

// ---------------------------------------------------------------------- K3
// 128 blocks x 512 threads, active iff bid%8<4 (64 roles). r=bid%8, c=bid>>3.
// 96 KB dummy dynamic LDS preserves 1-block/CU placement (R4-R7-verified).
__global__ __launch_bounds__(512, 2) void k_recur(uint8_t* ws,
                                                  const int* __restrict__ vlen,
                                                  float* __restrict__ out) {
  int bid = blockIdx.x;
  if ((bid & 7) >= 4) return;
  int r = bid & 7, c = bid >> 3;

  extern __shared__ uint8_t smem[];
  uint8_t*  slice_lds = smem;                              // 16 x 1024 B
  volatile uint32_t* flag = (volatile uint32_t*)(smem + 16384);  // 16 u32
  float*    tmp     = (float*)(smem + 16448);              // [16][132] f32
  uint32_t* pub_lds = (uint32_t*)(smem + 24896);           // 512 u32
  float*    c_lds   = (float*)(smem + 26944);              // 512 f32
  uint8_t*  g_lds   = smem + 28992;                        // 4096 B

  int tid = threadIdx.x, lane = tid & 63, wave = tid >> 6;

  if (tid < 16) flag[tid] = 0;

  const uint8_t* Gp = ws + G_OFF;
  uint8_t* hbuf = ws + HBUF_OFF;

  // ---- Wh B-fragments -> registers (ONCE; Wh time-invariant; R6-verified)
  bf16x8 Bfrag[16];
  {
    int cc = c * 128 + wave * 16 + (lane & 15);
    const uint8_t* wb = ws + WHR_OFF + (size_t)cc * 1024 + ((lane >> 4) << 4);
#pragma unroll
    for (int j = 0; j < 16; ++j)
      Bfrag[j] = *(const bf16x8*)(wb + j * 64);
  }

  int gb = tid >> 5, d = tid & 31;         // gate mapping: (batch gb, dim d)
  int gbatch = r * 16 + gb;
  float cr = 0.0f;

  // wave-7 store-lane constants (lane covers batch lane>>2, seg lane&3)
  int w7_batch = r * 16 + (lane >> 2);
  int w7_vl = vlen[w7_batch];
  uint4 g_regs0, g_regs1, g_regs2, g_regs3;   // G(t) staged for g_lds
  if (wave == 7) {
    const uint8_t* gp = Gp + (size_t)w7_batch * 4096 +
                        (size_t)(lane & 3) * 1024 + (size_t)c * 64;
    g_regs0 = *(const uint4*)(gp);
    g_regs1 = *(const uint4*)(gp + 16);
    g_regs2 = *(const uint4*)(gp + 32);
    g_regs3 = *(const uint4*)(gp + 48);
  }

  float* outH  = out;
  float* outLH = out + 8388608;
  float* outLC = out + 8421376;

  __syncthreads();   // startup only

  bool fb = false;   // sticky per-wave fallback (wave-uniform)
  for (int t = 0; t < 256; ++t) {
    const uint8_t* hbase = hbuf + (size_t)(t & 1) * 131072 + (size_t)r * 32768;
    uint32_t expect = (uint32_t)((t >> 1) & 1);

    if (wave < 7) {
      // ---- polling duties: validate slice j, cvt to A-frag layout, flag it
      auto poll_slice = [&](int j) {
        const uint8_t* sp = hbase + (size_t)(lane & 15) * 2048 +
                            (size_t)(j * 128 + ((lane >> 4) << 5));
        uint64_t y0, y1, y2, y3;
        int passes = 0;
        for (;;) {
          if (!fb) {
            asm volatile(
              "global_load_dwordx2 %0, %4, off sc0\n\t"
              "global_load_dwordx2 %1, %5, off sc0\n\t"
              "global_load_dwordx2 %2, %6, off sc0\n\t"
              "global_load_dwordx2 %3, %7, off sc0\n\t"
              "s_waitcnt vmcnt(0)"
              : "=v"(y0), "=v"(y1), "=v"(y2), "=v"(y3)
              : "v"(sp), "v"(sp + 8), "v"(sp + 16), "v"(sp + 24)
              : "memory");
            __builtin_amdgcn_sched_barrier(0);
          } else {
            y0 = __hip_atomic_load((const uint64_t*)(sp),      __ATOMIC_RELAXED, __HIP_MEMORY_SCOPE_AGENT);
            y1 = __hip_atomic_load((const uint64_t*)(sp + 8),  __ATOMIC_RELAXED, __HIP_MEMORY_SCOPE_AGENT);
            y2 = __hip_atomic_load((const uint64_t*)(sp + 16), __ATOMIC_RELAXED, __HIP_MEMORY_SCOPE_AGENT);
            y3 = __hip_atomic_load((const uint64_t*)(sp + 24), __ATOMIC_RELAXED, __HIP_MEMORY_SCOPE_AGENT);
          }
          uint32_t bad = (((uint32_t)y0 ^ expect) | ((uint32_t)(y0 >> 32) ^ expect) |
                          ((uint32_t)y1 ^ expect) | ((uint32_t)(y1 >> 32) ^ expect) |
                          ((uint32_t)y2 ^ expect) | ((uint32_t)(y2 >> 32) ^ expect) |
                          ((uint32_t)y3 ^ expect) | ((uint32_t)(y3 >> 32) ^ expect)) & 1u;
          if (__ballot(bad) == 0ULL) break;
          if (++passes > 4096) fb = true;   // bounded: degrade, never hang
        }
        uint4 v; v.x = pkbf(y0); v.y = pkbf(y1); v.z = pkbf(y2); v.w = pkbf(y3);
        *(uint4*)(slice_lds + j * 1024 + lane * 16) = v;
        asm volatile("s_waitcnt lgkmcnt(0)" ::: "memory");
        __builtin_amdgcn_sched_barrier(0);
        if (lane == 0) flag[j] = (uint32_t)(t + 1);
      };
      poll_slice(wave);
      poll_slice(wave + 7);
      if (wave < 2) poll_slice(14 + wave);
    } else {
      // ---- wave 7 (store wave): g_lds = G(t) from regs (loads landed long ago)
      {
        uint8_t* gl = g_lds + (lane >> 2) * 256 + (lane & 3) * 64;
        *(uint4*)(gl)      = g_regs0;
        *(uint4*)(gl + 16) = g_regs1;
        *(uint4*)(gl + 32) = g_regs2;
        *(uint4*)(gl + 48) = g_regs3;
      }
      // ---- mirror (agent, fallback liveness) + outH + last for h_t (t>0)
      if (t > 0) {
        const uint2* ps = (const uint2*)(pub_lds + lane * 8);
        uint2 p0 = ps[0], p1 = ps[1], p2 = ps[2], p3 = ps[3];
        uint8_t* mb = (uint8_t*)hbase + (size_t)(lane >> 2) * 2048 +
                      (size_t)c * 128 + (size_t)(lane & 3) * 32;
        __hip_atomic_store((uint64_t*)(mb),      ((uint64_t)p0.y << 32) | p0.x, __ATOMIC_RELAXED, __HIP_MEMORY_SCOPE_AGENT);
        __hip_atomic_store((uint64_t*)(mb + 8),  ((uint64_t)p1.y << 32) | p1.x, __ATOMIC_RELAXED, __HIP_MEMORY_SCOPE_AGENT);
        __hip_atomic_store((uint64_t*)(mb + 16), ((uint64_t)p2.y << 32) | p2.x, __ATOMIC_RELAXED, __HIP_MEMORY_SCOPE_AGENT);
        __hip_atomic_store((uint64_t*)(mb + 24), ((uint64_t)p3.y << 32) | p3.x, __ATOMIC_RELAXED, __HIP_MEMORY_SCOPE_AGENT);
        // outH row t-1 (tag bit0 error ~2^-23: negligible vs 4.4e-4)
        uint32_t* oh = (uint32_t*)outH +
                       ((size_t)w7_batch * 256 + (size_t)(t - 1)) * 512 +
                       (size_t)c * 32 + (size_t)(lane & 3) * 8;
        uint4 a; a.x = p0.x; a.y = p0.y; a.z = p1.x; a.w = p1.y;
        uint4 b; b.x = p2.x; b.y = p2.y; b.z = p3.x; b.w = p3.y;
        *(uint4*)(oh) = a;
        *(uint4*)(oh + 4) = b;
        if (t - 1 == w7_vl - 1) {
          size_t lb = (size_t)w7_batch * 512 + (size_t)c * 32 + (size_t)(lane & 3) * 8;
          *(uint4*)((uint32_t*)outLH + lb) = a;
          *(uint4*)((uint32_t*)outLH + lb + 4) = b;
          const float4* cs = (const float4*)(c_lds + lane * 8);
          *(float4*)(outLC + lb) = cs[0];
          *(float4*)(outLC + lb + 4) = cs[1];
        }
      }
      // ---- issue G(t+1) loads (HBM; consumed at g_lds write next step)
      {
        const uint8_t* gp = Gp + (size_t)((t + 1) & 255) * 262144 +
                            (size_t)w7_batch * 4096 +
                            (size_t)(lane & 3) * 1024 + (size_t)c * 64;
        g_regs0 = *(const uint4*)(gp);
        g_regs1 = *(const uint4*)(gp + 16);
        g_regs2 = *(const uint4*)(gp + 32);
        g_regs3 = *(const uint4*)(gp + 48);
      }
    }

    // ---- consume 16 slices as they arrive (all 8 waves)
    f32x4 acc0 = f32x4{0.f, 0.f, 0.f, 0.f}, acc1 = acc0;
#pragma unroll
    for (int j = 0; j < 16; ++j) {
      while ((int)flag[j] < t + 1) { }
      asm volatile("" ::: "memory");
      bf16x8 a = *(const bf16x8*)(slice_lds + j * 1024 + lane * 16);
      if (j & 1) acc1 = __builtin_amdgcn_mfma_f32_16x16x32_bf16(a, Bfrag[j], acc1, 0, 0, 0);
      else       acc0 = __builtin_amdgcn_mfma_f32_16x16x32_bf16(a, Bfrag[j], acc0, 0, 0, 0);
    }
    {  // D layout: col=lane&15, row(batch)=(lane>>4)*4+q; stride 132 (2-way)
      int colb = wave * 16 + (lane & 15);
      int rowd = (lane >> 4) << 2;
#pragma unroll
      for (int q = 0; q < 4; ++q)
        tmp[(rowd + q) * 132 + colb] = acc0[q] + acc1[q];
    }
    BAR_LDS();                                     // B1

    // ---- gates (G from g_lds)
    float hval, cval;
    {
      const unsigned short* gg = (const unsigned short*)(g_lds + gb * 256 + d * 2);
      float ip = tmp[gb * 132 + d]      + bf2f(gg[0]);
      float fp = tmp[gb * 132 + d + 32] + bf2f(gg[32]);
      float op = tmp[gb * 132 + d + 64] + bf2f(gg[64]);
      float gp = tmp[gb * 132 + d + 96] + bf2f(gg[96]);
      float ig = fsigmoid(ip), fg = fsigmoid(fp), og = fsigmoid(op);
      float gt = ftanh(gp);
      cval = fg * cr + ig * gt;
      cr = cval;
      hval = og * ftanh(cval);
    }
    // ---- publish tagged h_{t+1}: plain store (same-XCD L2), prompt L2 ack
    {
      uint32_t wtag = (uint32_t)(((t + 1) >> 1) & 1);
      uint32_t pubw = (f2u(hval) & ~1u) | wtag;
      uint8_t* pub = hbuf + (size_t)((t + 1) & 1) * 131072 +
                     (size_t)gbatch * 2048 + (size_t)(c * 32 + d) * 4;
      asm volatile("global_store_dword %0, %1, off" :: "v"(pub), "v"(pubw) : "memory");
      pub_lds[tid] = pubw;       // route to wave 7 for mirror/outH next step
      c_lds[tid] = cval;
    }
    BAR_LDS();                                     // B2 (tmp/pub_lds WAR guard)
  }
  // ---- post-loop (wave 7): h_256 outputs
  if (wave == 7) {
    const uint2* ps = (const uint2*)(pub_lds + lane * 8);
    uint2 p0 = ps[0], p1 = ps[1], p2 = ps[2], p3 = ps[3];
    uint4 a; a.x = p0.x; a.y = p0.y; a.z = p1.x; a.w = p1.y;
    uint4 b; b.x = p2.x; b.y = p2.y; b.z = p3.x; b.w = p3.y;
    uint32_t* oh = (uint32_t*)outH + ((size_t)w7_batch * 256 + 255) * 512 +
                   (size_t)c * 32 + (size_t)(lane & 3) * 8;
    *(uint4*)(oh) = a;
    *(uint4*)(oh + 4) = b;
    if (w7_vl == 256) {
      size_t lb = (size_t)w7_batch * 512 + (size_t)c * 32 + (size_t)(lane & 3) * 8;
      *(uint4*)((uint32_t*)outLH + lb) = a;
      *(uint4*)((uint32_t*)outLH + lb + 4) = b;
      const float4* cs = (const float4*)(c_lds + lane * 8);
      *(float4*)(outLC + lb) = cs[0];
      *(float4*)(outLC + lb + 4) = cs[1];
    }
  }
}

// ---------------------------------------------------------------------------
extern "C" void kernel_launch(void* const* d_in, const int* in_sizes, int n_in,
                              void* d_out, int out_size, void* d_ws, size_t ws_size,
                              hipStream_t stream) {
  const int*   loc     = (const int*)d_in[0];
  const int*   tdu     = (const int*)d_in[1];
  const int*   tdl     = (const int*)d_in[2];
  const int*   sdu     = (const int*)d_in[3];
  const int*   sdl     = (const int*)d_in[4];
  const int*   vlen    = (const int*)d_in[5];
  const float* loc_emb = (const float*)d_in[6];
  const float* tup     = (const float*)d_in[7];
  const float* tlo     = (const float*)d_in[8];
  const float* sup     = (const float*)d_in[9];
  const float* slo     = (const float*)d_in[10];
  const float* Wt      = (const float*)d_in[11];
  const float* Ws      = (const float*)d_in[12];
  const float* Wi      = (const float*)d_in[13];
  const float* bi      = (const float*)d_in[14];
  const float* Wh      = (const float*)d_in[15];
  uint8_t* ws = (uint8_t*)d_ws;
  float* out = (float*)d_out;

  if (ws_size < WS_NEED) return;  // need ~120.2 MiB scratch

  (void)hipFuncSetAttribute((const void*)k_recur,
                            hipFuncAttributeMaxDynamicSharedMemorySize, 98304);

  k_prep  <<<2112, 256, 0, stream>>>(Wi, Wt, Ws, Wh, ws);
  k_gather<<<16384, 192, 0, stream>>>(loc, tdu, tdl, sdu, sdl,
                                      loc_emb, tup, tlo, sup, slo, ws);
  k_gemm  <<<2048, 256, 0, stream>>>(ws, bi);
  k_recur <<<128, 512, 98304, stream>>>(ws, vlen, out);
}

// Round 9
// 1525.291 us; speedup vs baseline: 5.8708x; 5.8708x over previous
//
#include <hip/hip_runtime.h>
#include <stdint.h>

// ---------------------------------------------------------------------------
// ST-LSTM on MI355X.
//  K0 k_prep   : W_catT (2048x1536 bf16, T+XOR-swizzled), Wh_rearr (2048x512
//                bf16, col-reordered, linear), h buf0=0 (tag0 valid),
//                buf1=1 (tag1), distress=0.
//  K1 k_gather : A_cat (16384x1536 bf16, swizzled) = [x | q/3600 | sp/1000].
//  K2 k_gemm   : G bf16 = A_cat @ W_cat + bi, laid out [t][b][dim*4+gate]
//                (gates of one dim adjacent -> recurrence reads one u64).
//  K3 k_recur  : 64 active roles from 128 blocks (bid%8<4): r=bid%8, c=bid>>3;
//                r-group shares one XCD L2 (round-robin dispatch; verified
//                R4-R6 via FETCH collapse). Tagged-h polling (parity bit0).
//                FAST MODE: publish/outH = plain stores (L2-class acks only),
//                one vmcnt(0)/step; NO agent traffic on any polling wave
//                (R4-R6's 2us/step agent-ack entanglement removed; R7/R8's
//                same-address lazy-mirror race eliminated by having NO mirror).
//                FALLBACK: stuck wave (>1024 passes) sets distress (IC),
//                agent-republishes its own last word (same-lane same-address
//                -> ordered), switches to agent polling + dual publish;
//                healthy waves poll distress every 16 steps. Bounded, no hang.
//
// ws layout (bytes), total need = 126,091,520 (~120.2 MiB):
#define A_CAT_OFF  0ull                  // 16384*3072
#define WCT_OFF    50331648ull           // 2048*3072
#define WHR_OFF    56623104ull           // 2048*1024 (linear)
#define G_OFF      58720256ull           // 16384*2048*2
#define HBUF_OFF   125829120ull          // 2 bufs x 64 batches x 512 f32 (tagged)
#define DIST_OFF   126091264ull          // 4 r-groups x 64B distress lines
#define WS_NEED    126091520ull

typedef short bf16x8 __attribute__((ext_vector_type(8)));
typedef float f32x4  __attribute__((ext_vector_type(4)));
typedef uint32_t u32x4 __attribute__((ext_vector_type(4)));

__device__ __forceinline__ unsigned short f2bf(float f) {
  union { float f; uint32_t u; } v; v.f = f;
  uint32_t u = v.u;
  u += 0x7FFFu + ((u >> 16) & 1u);   // RNE
  return (unsigned short)(u >> 16);
}
__device__ __forceinline__ float bf2f(unsigned short h) {
  union { uint32_t u; float f; } v; v.u = ((uint32_t)h) << 16;
  return v.f;
}
__device__ __forceinline__ float u2f(uint32_t u) {
  union { uint32_t u; float f; } v; v.u = u; return v.f;
}
__device__ __forceinline__ uint32_t f2u(float f) {
  union { float f; uint32_t u; } v; v.f = f; return v.u;
}
__device__ __forceinline__ float fsigmoid(float x) { return 1.0f / (1.0f + __expf(-x)); }
__device__ __forceinline__ float ftanh(float x) {
  float e = __expf(2.0f * x);
  return 1.0f - 2.0f / (e + 1.0f);
}
__device__ __forceinline__ uint4 pack8(const unsigned short* v) {
  uint4 r;
  r.x = (uint32_t)v[0] | ((uint32_t)v[1] << 16);
  r.y = (uint32_t)v[2] | ((uint32_t)v[3] << 16);
  r.z = (uint32_t)v[4] | ((uint32_t)v[5] << 16);
  r.w = (uint32_t)v[6] | ((uint32_t)v[7] << 16);
  return r;
}
__device__ __forceinline__ uint32_t pk2(uint32_t a, uint32_t b) {
  return (uint32_t)f2bf(u2f(a)) | ((uint32_t)f2bf(u2f(b)) << 16);
}

#define GLOAD_LDS16(GP, LP)                                                   \
  __builtin_amdgcn_global_load_lds(                                          \
      (const __attribute__((address_space(1))) uint32_t*)(GP),               \
      (__attribute__((address_space(3))) uint32_t*)(LP), 16, 0, 0)

// LDS-only barrier (no vmcnt drain)
#define BAR_LDS()                                                             \
  do {                                                                        \
    asm volatile("s_waitcnt lgkmcnt(0)" ::: "memory");                        \
    __builtin_amdgcn_sched_barrier(0);                                        \
    __builtin_amdgcn_s_barrier();                                             \
  } while (0)

// ---------------------------------------------------------------------- K0
__global__ __launch_bounds__(256) void k_prep(
    const float* __restrict__ Wi, const float* __restrict__ Wt,
    const float* __restrict__ Ws, const float* __restrict__ Wh,
    uint8_t* ws) {
  int id = blockIdx.x * 256 + threadIdx.x;
  if (id < 393216) {                       // W_catT: 2048 cols x 192 k-chunks
    int n  = id & 2047;
    int k0 = (id >> 11) << 3;
    unsigned short v[8];
#pragma unroll
    for (int j = 0; j < 8; ++j) {
      int k = k0 + j;
      float x;
      if (k < 512)       x = Wi[k * 2048 + n];
      else if (k < 1024) x = (n < 1536) ? Wt[(k - 512) * 1536 + n] : 0.0f;
      else               x = (n < 1536) ? Ws[(k - 1024) * 1536 + n] : 0.0f;
      v[j] = f2bf(x);
    }
    size_t off = WCT_OFF + (size_t)n * 3072 +
                 (size_t)(((uint32_t)k0 * 2u) ^ (((uint32_t)n & 7u) << 4));
    *(uint4*)(ws + off) = pack8(v);
  } else if (id < 524288) {                // Wh_rearr: LINEAR (reg-consumed)
    int id2 = id - 393216;
    int cc  = id2 & 2047;
    int k0  = (id2 >> 11) << 3;
    int col = ((cc >> 5) & 3) * 512 + (cc >> 7) * 32 + (cc & 31);
    unsigned short v[8];
#pragma unroll
    for (int j = 0; j < 8; ++j) v[j] = f2bf(Wh[(size_t)(k0 + j) * 2048 + col]);
    *(uint4*)(ws + WHR_OFF + (size_t)cc * 1024 + (size_t)k0 * 2) = pack8(v);
  } else if (id < 532480) {                // buf0 = h_0 = +0.0f (tag 0, valid)
    uint4 z; z.x = z.y = z.z = z.w = 0u;
    *(uint4*)(ws + HBUF_OFF + (size_t)(id - 524288) * 16) = z;
  } else if (id < 540672) {                // buf1 = tag 1 (invalid for t=1)
    uint4 z; z.x = z.y = z.z = z.w = 1u;
    *(uint4*)(ws + HBUF_OFF + 131072ull + (size_t)(id - 532480) * 16) = z;
  } else if (id < 540688) {                // distress lines = 0
    uint4 z; z.x = z.y = z.z = z.w = 0u;
    *(uint4*)(ws + DIST_OFF + (size_t)(id - 540672) * 16) = z;
  }
}

// ---------------------------------------------------------------------- K1
__global__ __launch_bounds__(192) void k_gather(
    const int* __restrict__ loc, const int* __restrict__ tdu,
    const int* __restrict__ tdl, const int* __restrict__ sdu,
    const int* __restrict__ sdl,
    const float* __restrict__ loc_emb, const float* __restrict__ tup,
    const float* __restrict__ tlo, const float* __restrict__ sup,
    const float* __restrict__ slo, uint8_t* ws) {
  int m  = blockIdx.x;        // row = b*256 + t
  int t  = m & 255;
  int k0 = threadIdx.x << 3;  // 192 chunks of 8
  float vals[8];
  if (k0 < 512) {
    const float* s = loc_emb + (size_t)loc[m] * 512 + k0;
#pragma unroll
    for (int j = 0; j < 8; ++j) vals[j] = s[j];
  } else if (k0 < 1024) {
    int e = k0 - 512;
    const float* a = tup + (size_t)tdu[m] * 512 + e;
    const float* b = tlo + (size_t)tdl[m] * 512 + e;
    float sc = (t > 0) ? (1.0f / 3600.0f) : 0.0f;
#pragma unroll
    for (int j = 0; j < 8; ++j) vals[j] = (a[j] + b[j]) * sc;
  } else {
    int e = k0 - 1024;
    const float* a = sup + (size_t)sdu[m] * 512 + e;
    const float* b = slo + (size_t)sdl[m] * 512 + e;
    float sc = (t > 0) ? (1.0f / 1000.0f) : 0.0f;
#pragma unroll
    for (int j = 0; j < 8; ++j) vals[j] = (a[j] + b[j]) * sc;
  }
  unsigned short v[8];
#pragma unroll
  for (int j = 0; j < 8; ++j) v[j] = f2bf(vals[j]);
  size_t off = A_CAT_OFF + (size_t)m * 3072 +
               (size_t)(((uint32_t)k0 * 2u) ^ (((uint32_t)m & 7u) << 4));
  *(uint4*)(ws + off) = pack8(v);
}

// ---------------------------------------------------------------------- K2
__global__ __launch_bounds__(256) void k_gemm(uint8_t* ws,
                                              const float* __restrict__ bi) {
  __shared__ uint8_t A_lds[16384];   // 128 rows x 64 k bf16 (swizzled content)
  __shared__ uint8_t B_lds[16384];   // 128 cols x 64 k bf16
  const uint8_t* Acat = ws + A_CAT_OFF;
  const uint8_t* Wct  = ws + WCT_OFF;
  uint8_t* Gp = ws + G_OFF;
  int tid = threadIdx.x;
  int lane = tid & 63, wave = tid >> 6;
  int wm = wave >> 1, wn = wave & 1;
  int tile_m = blockIdx.x >> 4, tile_n = blockIdx.x & 15;

  f32x4 acc[4][4];
#pragma unroll
  for (int m = 0; m < 4; ++m)
#pragma unroll
    for (int n = 0; n < 4; ++n) acc[m][n] = f32x4{0.f, 0.f, 0.f, 0.f};

  for (int kb = 0; kb < 1536; kb += 64) {
#pragma unroll
    for (int i = 0; i < 4; ++i) {
      int lidx = i * 256 + tid;
      int row = lidx >> 3, ch = lidx & 7;
      GLOAD_LDS16(Acat + (size_t)(tile_m * 128 + row) * 3072 + kb * 2 + ch * 16,
                  A_lds + (i * 256 + wave * 64) * 16);
    }
#pragma unroll
    for (int i = 0; i < 4; ++i) {
      int lidx = i * 256 + tid;
      int row = lidx >> 3, ch = lidx & 7;
      GLOAD_LDS16(Wct + (size_t)(tile_n * 128 + row) * 3072 + kb * 2 + ch * 16,
                  B_lds + (i * 256 + wave * 64) * 16);
    }
    __syncthreads();
#pragma unroll
    for (int kk = 0; kk < 2; ++kk) {
      int koff = kk * 64 + ((lane >> 4) << 4);
      bf16x8 af[4], bfr[4];
#pragma unroll
      for (int m = 0; m < 4; ++m) {
        int row = wm * 64 + m * 16 + (lane & 15);
        af[m] = *(const bf16x8*)(A_lds + row * 128 + (koff ^ ((row & 7) << 4)));
      }
#pragma unroll
      for (int n = 0; n < 4; ++n) {
        int row = wn * 64 + n * 16 + (lane & 15);
        bfr[n] = *(const bf16x8*)(B_lds + row * 128 + (koff ^ ((row & 7) << 4)));
      }
#pragma unroll
      for (int m = 0; m < 4; ++m)
#pragma unroll
        for (int n = 0; n < 4; ++n)
          acc[m][n] = __builtin_amdgcn_mfma_f32_16x16x32_bf16(af[m], bfr[n],
                                                              acc[m][n], 0, 0, 0);
    }
    __syncthreads();
  }
  // epilogue: + bias, bf16, scatter to G laid out [t][b][dim*4 + gate]
  int lr = lane >> 4, lc = lane & 15;
#pragma unroll
  for (int n = 0; n < 4; ++n) {
    int gcol = tile_n * 128 + wn * 64 + n * 16 + lc;
    float bv = bi[gcol];
    int gidx = (gcol & 511) * 4 + (gcol >> 9);     // dim*4 + gate
#pragma unroll
    for (int m = 0; m < 4; ++m) {
      int growb = tile_m * 128 + wm * 64 + m * 16 + lr * 4;
#pragma unroll
      for (int q = 0; q < 4; ++q) {
        int grow = growb + q;                      // = b*256 + t
        float v = acc[m][n][q] + bv;
        size_t gi = ((size_t)(grow & 255) * 64 + (size_t)(grow >> 8)) * 2048 + gidx;
        *(unsigned short*)(Gp + gi * 2) = f2bf(v);
      }
    }
  }
}

// ---------------------------------------------------------------------- K3
// 128 blocks x 512 threads, active iff bid%8<4 (64 roles). r=bid%8, c=bid>>3.
// 96 KB dummy dynamic LDS preserves 1-block/CU placement (R4-R6-verified).
__global__ __launch_bounds__(512, 2) void k_recur(uint8_t* ws,
                                                  const int* __restrict__ vlen,
                                                  float* __restrict__ out) {
  int bid = blockIdx.x;
  if ((bid & 7) >= 4) return;
  int r = bid & 7, c = bid >> 3;

  extern __shared__ uint8_t smem[];
  uint8_t* h_lds = smem;                    // [16][512] bf16 permuted, 16384 B
  float*   tmp   = (float*)(smem + 16384);  // [16][132] f32, 8448 B

  int tid = threadIdx.x;
  int lane = tid & 63, wave = tid >> 6;

  const uint8_t* Gp = ws + G_OFF;
  uint8_t* hbuf = ws + HBUF_OFF;
  uint32_t* dist = (uint32_t*)(ws + DIST_OFF + (size_t)r * 64);

  // ---- Wh B-fragments -> registers (ONCE; Wh time-invariant; R6-verified)
  bf16x8 Bfrag[16];
  {
    int cc = c * 128 + wave * 16 + (lane & 15);
    const uint8_t* wb = ws + WHR_OFF + (size_t)cc * 1024 + ((lane >> 4) << 4);
#pragma unroll
    for (int kk = 0; kk < 16; ++kk)
      Bfrag[kk] = *(const bf16x8*)(wb + kk * 64);
  }

  int gb = tid >> 5, d = tid & 31;         // gate mapping: (batch gb, dim d)
  int gbatch = r * 16 + gb;
  int vl = vlen[gbatch];
  float cr = 0.0f;
  uint32_t pubw_prev = 0;                  // word published last step (h_0=0,tag0)
  bool fb = false;                         // sticky fallback (agent mode)

  int hb_b = 2 * wave + (lane >> 5);       // poll/cvt: batch row
  int w0 = lane & 31;                      // poll/cvt: 16-dim slice index

  float* outH  = out;
  float* outLH = out + 8388608;
  float* outLC = out + 8421376;

  __syncthreads();   // startup only

  for (int t = 0; t < 256; ++t) {
    uint8_t* mybuf = hbuf + (size_t)(t & 1) * 131072;  // holds h_t
    uint32_t* mypub = (uint32_t*)(mybuf + (size_t)gbatch * 2048 +
                                  (size_t)(c * 32 + d) * 4);
    // ---- distress check every 16 steps (fast mode only)
    if (!fb && (t & 15) == 0) {
      uint32_t dv = __hip_atomic_load(dist, __ATOMIC_RELAXED,
                                      __HIP_MEMORY_SCOPE_AGENT);
      if (__ballot(dv != 0) != 0ULL) {
        fb = true;
        __hip_atomic_store(mypub, pubw_prev, __ATOMIC_RELAXED,
                           __HIP_MEMORY_SCOPE_AGENT);   // republish h_t (ordered)
      }
    }
    // ---- poll tagged h_t
    u32x4 x0, x1, x2, x3;
    {
      const uint8_t* hb = mybuf + (size_t)r * 32768 +
                          (size_t)hb_b * 2048 + (size_t)w0 * 64;
      uint32_t expect = (uint32_t)((t >> 1) & 1);
      int passes = 0;
      for (;;) {
        if (!fb) {
          asm volatile(
            "global_load_dwordx4 %0, %4, off sc0\n\t"
            "global_load_dwordx4 %1, %5, off sc0\n\t"
            "global_load_dwordx4 %2, %6, off sc0\n\t"
            "global_load_dwordx4 %3, %7, off sc0\n\t"
            "s_waitcnt vmcnt(0)"
            : "=v"(x0), "=v"(x1), "=v"(x2), "=v"(x3)
            : "v"(hb), "v"(hb + 16), "v"(hb + 32), "v"(hb + 48)
            : "memory");
          __builtin_amdgcn_sched_barrier(0);
        } else {
          uint64_t y[8];
#pragma unroll
          for (int i = 0; i < 8; ++i)
            y[i] = __hip_atomic_load((const uint64_t*)(hb + i * 8),
                                     __ATOMIC_RELAXED, __HIP_MEMORY_SCOPE_AGENT);
          x0 = u32x4{(uint32_t)y[0], (uint32_t)(y[0] >> 32), (uint32_t)y[1], (uint32_t)(y[1] >> 32)};
          x1 = u32x4{(uint32_t)y[2], (uint32_t)(y[2] >> 32), (uint32_t)y[3], (uint32_t)(y[3] >> 32)};
          x2 = u32x4{(uint32_t)y[4], (uint32_t)(y[4] >> 32), (uint32_t)y[5], (uint32_t)(y[5] >> 32)};
          x3 = u32x4{(uint32_t)y[6], (uint32_t)(y[6] >> 32), (uint32_t)y[7], (uint32_t)(y[7] >> 32)};
        }
        uint32_t bad = 0;
#pragma unroll
        for (int e = 0; e < 4; ++e)
          bad |= (x0[e] ^ expect) | (x1[e] ^ expect) |
                 (x2[e] ^ expect) | (x3[e] ^ expect);
        if (__ballot((bad & 1u) != 0u) == 0ULL) break;
        if (++passes > 1024) {             // bounded: degrade, never hang
          passes = 0;
          if (!fb) {
            fb = true;
            __hip_atomic_store(dist, 1u, __ATOMIC_RELAXED,
                               __HIP_MEMORY_SCOPE_AGENT);
          }
          // (re)publish our h_t word via IC; same lane+address => ordered
          __hip_atomic_store(mypub, pubw_prev, __ATOMIC_RELAXED,
                             __HIP_MEMORY_SCOPE_AGENT);
        }
      }
    }
    // ---- G for THIS step (one u64: i,f,o,g of dim c*32+d; lands under MFMA)
    uint64_t gx = *(const uint64_t*)(Gp + ((size_t)(t * 64 + gbatch) * 2048 +
                                           (size_t)(c * 32 + d) * 4) * 2);
    // ---- cvt f32->bf16, write permuted h_lds: chunk F(c)=c^(c>>3)^(row&7)
    {
      uint4 v0, v1;
      v0.x = pk2(x0[0], x0[1]); v0.y = pk2(x0[2], x0[3]);
      v0.z = pk2(x1[0], x1[1]); v0.w = pk2(x1[2], x1[3]);
      v1.x = pk2(x2[0], x2[1]); v1.y = pk2(x2[2], x2[3]);
      v1.z = pk2(x3[0], x3[1]); v1.w = pk2(x3[2], x3[3]);
      int s = hb_b & 7;
      int c0 = (2 * w0) ^ (w0 >> 2) ^ s;     // logical chunks 2w0, 2w0+1
      int c1 = c0 ^ 1;
      *(uint4*)(h_lds + hb_b * 1024 + c0 * 16) = v0;
      *(uint4*)(h_lds + hb_b * 1024 + c1 * 16) = v1;
    }
    BAR_LDS();                                     // B1

    // ---- MFMA: tmp(16 x wave's 16 cols) = h(16x512) @ Wh_regs (2 acc chains)
    f32x4 acc0 = f32x4{0.f, 0.f, 0.f, 0.f}, acc1 = acc0;
    {
      int lrow = lane & 15;
      int g = lane >> 4;
      int gs = (g ^ (lrow & 7)) * 16;
#pragma unroll
      for (int kk = 0; kk < 16; kk += 2) {
        int k0c = ((kk * 4) ^ (kk >> 1)) * 16;         // compile-time
        int k1c = (((kk + 1) * 4) ^ ((kk + 1) >> 1)) * 16;
        bf16x8 a0 = *(const bf16x8*)(h_lds + lrow * 1024 + (k0c ^ gs));
        bf16x8 a1 = *(const bf16x8*)(h_lds + lrow * 1024 + (k1c ^ gs));
        acc0 = __builtin_amdgcn_mfma_f32_16x16x32_bf16(a0, Bfrag[kk], acc0, 0, 0, 0);
        acc1 = __builtin_amdgcn_mfma_f32_16x16x32_bf16(a1, Bfrag[kk + 1], acc1, 0, 0, 0);
      }
    }
    {  // D layout: col=lane&15, row(batch)=(lane>>4)*4+q; stride 132 (2-way)
      int colb = wave * 16 + (lane & 15);
      int rowd = (lane >> 4) << 2;
#pragma unroll
      for (int q = 0; q < 4; ++q)
        tmp[(rowd + q) * 132 + colb] = acc0[q] + acc1[q];
    }
    BAR_LDS();                                     // B2

    // ---- gates
    float hval, cval;
    {
      int tb = gb * 132 + d;
      float ip = tmp[tb]      + bf2f((unsigned short)(gx & 0xFFFF));
      float fp = tmp[tb + 32] + bf2f((unsigned short)((gx >> 16) & 0xFFFF));
      float op = tmp[tb + 64] + bf2f((unsigned short)((gx >> 32) & 0xFFFF));
      float gp = tmp[tb + 96] + bf2f((unsigned short)((gx >> 48) & 0xFFFF));
      float ig = fsigmoid(ip), fg = fsigmoid(fp), og = fsigmoid(op);
      float gt = ftanh(gp);
      cval = fg * cr + ig * gt;
      cr = cval;
      hval = og * ftanh(cval);
    }
    // ---- publish h_{t+1} (plain, L2) + outputs; ONE vmcnt(0) (L2 acks only)
    {
      uint32_t wtag = (uint32_t)(((t + 1) >> 1) & 1);
      uint32_t pubw = (f2u(hval) & ~1u) | wtag;
      uint32_t* pub = (uint32_t*)(hbuf + (size_t)((t + 1) & 1) * 131072 +
                                  (size_t)gbatch * 2048 + (size_t)(c * 32 + d) * 4);
      asm volatile("global_store_dword %0, %1, off" :: "v"(pub), "v"(pubw) : "memory");
      if (fb)
        __hip_atomic_store(pub, pubw, __ATOMIC_RELAXED, __HIP_MEMORY_SCOPE_AGENT);
      pubw_prev = pubw;
      outH[((size_t)gbatch * 256 + (size_t)t) * 512 + (size_t)(c * 32 + d)] = hval;
      if (t == vl - 1) {
        size_t lb = (size_t)gbatch * 512 + (size_t)(c * 32 + d);
        outLH[lb] = hval;
        outLC[lb] = cval;
      }
      asm volatile("s_waitcnt vmcnt(0)" ::: "memory");  // flush (all L2-class)
      __builtin_amdgcn_sched_barrier(0);
    }
  }
}

// ---------------------------------------------------------------------------
extern "C" void kernel_launch(void* const* d_in, const int* in_sizes, int n_in,
                              void* d_out, int out_size, void* d_ws, size_t ws_size,
                              hipStream_t stream) {
  const int*   loc     = (const int*)d_in[0];
  const int*   tdu     = (const int*)d_in[1];
  const int*   tdl     = (const int*)d_in[2];
  const int*   sdu     = (const int*)d_in[3];
  const int*   sdl     = (const int*)d_in[4];
  const int*   vlen    = (const int*)d_in[5];
  const float* loc_emb = (const float*)d_in[6];
  const float* tup     = (const float*)d_in[7];
  const float* tlo     = (const float*)d_in[8];
  const float* sup     = (const float*)d_in[9];
  const float* slo     = (const float*)d_in[10];
  const float* Wt      = (const float*)d_in[11];
  const float* Ws      = (const float*)d_in[12];
  const float* Wi      = (const float*)d_in[13];
  const float* bi      = (const float*)d_in[14];
  const float* Wh      = (const float*)d_in[15];
  uint8_t* ws = (uint8_t*)d_ws;
  float* out = (float*)d_out;

  if (ws_size < WS_NEED) return;  // need ~120.2 MiB scratch

  (void)hipFuncSetAttribute((const void*)k_recur,
                            hipFuncAttributeMaxDynamicSharedMemorySize, 98304);

  k_prep  <<<2113, 256, 0, stream>>>(Wi, Wt, Ws, Wh, ws);
  k_gather<<<16384, 192, 0, stream>>>(loc, tdu, tdl, sdu, sdl,
                                      loc_emb, tup, tlo, sup, slo, ws);
  k_gemm  <<<2048, 256, 0, stream>>>(ws, bi);
  k_recur <<<128, 512, 98304, stream>>>(ws, vlen, out);
}

// Round 10
// 1368.567 us; speedup vs baseline: 6.5431x; 1.1145x over previous
//
#include <hip/hip_runtime.h>
#include <stdint.h>

// ---------------------------------------------------------------------------
// ST-LSTM on MI355X.
//  K0 k_prep   : W_catT (2048x1536 bf16, T+XOR-swizzled), Wh_rearr (2048x512
//                bf16, col-reordered, linear), h buf0=0 (tag0 valid),
//                buf1=1 (tag1), distress=0.
//  K1 k_gather : A_cat (16384x1536 bf16, swizzled) = [x | q/3600 | sp/1000].
//  K2 k_gemm   : G bf16 = A_cat @ W_cat + bi, laid out [t][b][dim*4+gate].
//  K3 k_recur  : 64 active roles from 128 blocks (bid%8<4): r=bid%8, c=bid>>3,
//                576 threads = 8 compute waves + 1 STORE WAVE.
//                Compute waves: tagged-h poll (sc0, L2) -> cvt -> MFMA ->
//                gates (G from LDS) -> publish (plain store, immediate
//                vmcnt(0) = L2 ack) -> stage h/c to LDS. They issue ZERO
//                HBM-class vmem ops, so no step ever drains an HBM/IC ack
//                (the R4-R9 invariant cost). Store wave: G(t+2) HBM prefetch
//                -> LDS double buffer, outH/last_h/last_c writes one step
//                behind from LDS staging. No mirror (R8's race removed).
//                Fallback: distress checked only in slow polls (passes==64);
//                stuck wave (>1024) sets distress + agent-republishes own
//                word (same lane+address = ordered), switches to agent
//                polling + dual publish. Bounded, no hang.
//
// ws layout (bytes), total need = 126,091,520 (~120.2 MiB):
#define A_CAT_OFF  0ull                  // 16384*3072
#define WCT_OFF    50331648ull           // 2048*3072
#define WHR_OFF    56623104ull           // 2048*1024 (linear)
#define G_OFF      58720256ull           // 16384*2048*2
#define HBUF_OFF   125829120ull          // 2 bufs x 64 batches x 512 f32 (tagged)
#define DIST_OFF   126091264ull          // 4 r-groups x 64B distress lines
#define WS_NEED    126091520ull

typedef short bf16x8 __attribute__((ext_vector_type(8)));
typedef float f32x4  __attribute__((ext_vector_type(4)));
typedef uint32_t u32x4 __attribute__((ext_vector_type(4)));

__device__ __forceinline__ unsigned short f2bf(float f) {
  union { float f; uint32_t u; } v; v.f = f;
  uint32_t u = v.u;
  u += 0x7FFFu + ((u >> 16) & 1u);   // RNE
  return (unsigned short)(u >> 16);
}
__device__ __forceinline__ float bf2f(unsigned short h) {
  union { uint32_t u; float f; } v; v.u = ((uint32_t)h) << 16;
  return v.f;
}
__device__ __forceinline__ float u2f(uint32_t u) {
  union { uint32_t u; float f; } v; v.u = u; return v.f;
}
__device__ __forceinline__ uint32_t f2u(float f) {
  union { float f; uint32_t u; } v; v.f = f; return v.u;
}
__device__ __forceinline__ float fsigmoid(float x) { return 1.0f / (1.0f + __expf(-x)); }
__device__ __forceinline__ float ftanh(float x) {
  float e = __expf(2.0f * x);
  return 1.0f - 2.0f / (e + 1.0f);
}
__device__ __forceinline__ uint4 pack8(const unsigned short* v) {
  uint4 r;
  r.x = (uint32_t)v[0] | ((uint32_t)v[1] << 16);
  r.y = (uint32_t)v[2] | ((uint32_t)v[3] << 16);
  r.z = (uint32_t)v[4] | ((uint32_t)v[5] << 16);
  r.w = (uint32_t)v[6] | ((uint32_t)v[7] << 16);
  return r;
}
__device__ __forceinline__ uint32_t pk2(uint32_t a, uint32_t b) {
  return (uint32_t)f2bf(u2f(a)) | ((uint32_t)f2bf(u2f(b)) << 16);
}

#define GLOAD_LDS16(GP, LP)                                                   \
  __builtin_amdgcn_global_load_lds(                                          \
      (const __attribute__((address_space(1))) uint32_t*)(GP),               \
      (__attribute__((address_space(3))) uint32_t*)(LP), 16, 0, 0)

// LDS-only barrier (no vmcnt drain)
#define BAR_LDS()                                                             \
  do {                                                                        \
    asm volatile("s_waitcnt lgkmcnt(0)" ::: "memory");                        \
    __builtin_amdgcn_sched_barrier(0);                                        \
    __builtin_amdgcn_s_barrier();                                             \
  } while (0)

// ---------------------------------------------------------------------- K0
__global__ __launch_bounds__(256) void k_prep(
    const float* __restrict__ Wi, const float* __restrict__ Wt,
    const float* __restrict__ Ws, const float* __restrict__ Wh,
    uint8_t* ws) {
  int id = blockIdx.x * 256 + threadIdx.x;
  if (id < 393216) {                       // W_catT: 2048 cols x 192 k-chunks
    int n  = id & 2047;
    int k0 = (id >> 11) << 3;
    unsigned short v[8];
#pragma unroll
    for (int j = 0; j < 8; ++j) {
      int k = k0 + j;
      float x;
      if (k < 512)       x = Wi[k * 2048 + n];
      else if (k < 1024) x = (n < 1536) ? Wt[(k - 512) * 1536 + n] : 0.0f;
      else               x = (n < 1536) ? Ws[(k - 1024) * 1536 + n] : 0.0f;
      v[j] = f2bf(x);
    }
    size_t off = WCT_OFF + (size_t)n * 3072 +
                 (size_t)(((uint32_t)k0 * 2u) ^ (((uint32_t)n & 7u) << 4));
    *(uint4*)(ws + off) = pack8(v);
  } else if (id < 524288) {                // Wh_rearr: LINEAR (reg-consumed)
    int id2 = id - 393216;
    int cc  = id2 & 2047;
    int k0  = (id2 >> 11) << 3;
    int col = ((cc >> 5) & 3) * 512 + (cc >> 7) * 32 + (cc & 31);
    unsigned short v[8];
#pragma unroll
    for (int j = 0; j < 8; ++j) v[j] = f2bf(Wh[(size_t)(k0 + j) * 2048 + col]);
    *(uint4*)(ws + WHR_OFF + (size_t)cc * 1024 + (size_t)k0 * 2) = pack8(v);
  } else if (id < 532480) {                // buf0 = h_0 = +0.0f (tag 0, valid)
    uint4 z; z.x = z.y = z.z = z.w = 0u;
    *(uint4*)(ws + HBUF_OFF + (size_t)(id - 524288) * 16) = z;
  } else if (id < 540672) {                // buf1 = tag 1 (invalid for t=1)
    uint4 z; z.x = z.y = z.z = z.w = 1u;
    *(uint4*)(ws + HBUF_OFF + 131072ull + (size_t)(id - 532480) * 16) = z;
  } else if (id < 540688) {                // distress lines = 0
    uint4 z; z.x = z.y = z.z = z.w = 0u;
    *(uint4*)(ws + DIST_OFF + (size_t)(id - 540672) * 16) = z;
  }
}

// ---------------------------------------------------------------------- K1
__global__ __launch_bounds__(192) void k_gather(
    const int* __restrict__ loc, const int* __restrict__ tdu,
    const int* __restrict__ tdl, const int* __restrict__ sdu,
    const int* __restrict__ sdl,
    const float* __restrict__ loc_emb, const float* __restrict__ tup,
    const float* __restrict__ tlo, const float* __restrict__ sup,
    const float* __restrict__ slo, uint8_t* ws) {
  int m  = blockIdx.x;        // row = b*256 + t
  int t  = m & 255;
  int k0 = threadIdx.x << 3;  // 192 chunks of 8
  float vals[8];
  if (k0 < 512) {
    const float* s = loc_emb + (size_t)loc[m] * 512 + k0;
#pragma unroll
    for (int j = 0; j < 8; ++j) vals[j] = s[j];
  } else if (k0 < 1024) {
    int e = k0 - 512;
    const float* a = tup + (size_t)tdu[m] * 512 + e;
    const float* b = tlo + (size_t)tdl[m] * 512 + e;
    float sc = (t > 0) ? (1.0f / 3600.0f) : 0.0f;
#pragma unroll
    for (int j = 0; j < 8; ++j) vals[j] = (a[j] + b[j]) * sc;
  } else {
    int e = k0 - 1024;
    const float* a = sup + (size_t)sdu[m] * 512 + e;
    const float* b = slo + (size_t)sdl[m] * 512 + e;
    float sc = (t > 0) ? (1.0f / 1000.0f) : 0.0f;
#pragma unroll
    for (int j = 0; j < 8; ++j) vals[j] = (a[j] + b[j]) * sc;
  }
  unsigned short v[8];
#pragma unroll
  for (int j = 0; j < 8; ++j) v[j] = f2bf(vals[j]);
  size_t off = A_CAT_OFF + (size_t)m * 3072 +
               (size_t)(((uint32_t)k0 * 2u) ^ (((uint32_t)m & 7u) << 4));
  *(uint4*)(ws + off) = pack8(v);
}

// ---------------------------------------------------------------------- K2
__global__ __launch_bounds__(256) void k_gemm(uint8_t* ws,
                                              const float* __restrict__ bi) {
  __shared__ uint8_t A_lds[16384];   // 128 rows x 64 k bf16 (swizzled content)
  __shared__ uint8_t B_lds[16384];   // 128 cols x 64 k bf16
  const uint8_t* Acat = ws + A_CAT_OFF;
  const uint8_t* Wct  = ws + WCT_OFF;
  uint8_t* Gp = ws + G_OFF;
  int tid = threadIdx.x;
  int lane = tid & 63, wave = tid >> 6;
  int wm = wave >> 1, wn = wave & 1;
  int tile_m = blockIdx.x >> 4, tile_n = blockIdx.x & 15;

  f32x4 acc[4][4];
#pragma unroll
  for (int m = 0; m < 4; ++m)
#pragma unroll
    for (int n = 0; n < 4; ++n) acc[m][n] = f32x4{0.f, 0.f, 0.f, 0.f};

  for (int kb = 0; kb < 1536; kb += 64) {
#pragma unroll
    for (int i = 0; i < 4; ++i) {
      int lidx = i * 256 + tid;
      int row = lidx >> 3, ch = lidx & 7;
      GLOAD_LDS16(Acat + (size_t)(tile_m * 128 + row) * 3072 + kb * 2 + ch * 16,
                  A_lds + (i * 256 + wave * 64) * 16);
    }
#pragma unroll
    for (int i = 0; i < 4; ++i) {
      int lidx = i * 256 + tid;
      int row = lidx >> 3, ch = lidx & 7;
      GLOAD_LDS16(Wct + (size_t)(tile_n * 128 + row) * 3072 + kb * 2 + ch * 16,
                  B_lds + (i * 256 + wave * 64) * 16);
    }
    __syncthreads();
#pragma unroll
    for (int kk = 0; kk < 2; ++kk) {
      int koff = kk * 64 + ((lane >> 4) << 4);
      bf16x8 af[4], bfr[4];
#pragma unroll
      for (int m = 0; m < 4; ++m) {
        int row = wm * 64 + m * 16 + (lane & 15);
        af[m] = *(const bf16x8*)(A_lds + row * 128 + (koff ^ ((row & 7) << 4)));
      }
#pragma unroll
      for (int n = 0; n < 4; ++n) {
        int row = wn * 64 + n * 16 + (lane & 15);
        bfr[n] = *(const bf16x8*)(B_lds + row * 128 + (koff ^ ((row & 7) << 4)));
      }
#pragma unroll
      for (int m = 0; m < 4; ++m)
#pragma unroll
        for (int n = 0; n < 4; ++n)
          acc[m][n] = __builtin_amdgcn_mfma_f32_16x16x32_bf16(af[m], bfr[n],
                                                              acc[m][n], 0, 0, 0);
    }
    __syncthreads();
  }
  // epilogue: + bias, bf16, scatter to G laid out [t][b][dim*4 + gate]
  int lr = lane >> 4, lc = lane & 15;
#pragma unroll
  for (int n = 0; n < 4; ++n) {
    int gcol = tile_n * 128 + wn * 64 + n * 16 + lc;
    float bv = bi[gcol];
    int gidx = (gcol & 511) * 4 + (gcol >> 9);     // dim*4 + gate
#pragma unroll
    for (int m = 0; m < 4; ++m) {
      int growb = tile_m * 128 + wm * 64 + m * 16 + lr * 4;
#pragma unroll
      for (int q = 0; q < 4; ++q) {
        int grow = growb + q;                      // = b*256 + t
        float v = acc[m][n][q] + bv;
        size_t gi = ((size_t)(grow & 255) * 64 + (size_t)(grow >> 8)) * 2048 + gidx;
        *(unsigned short*)(Gp + gi * 2) = f2bf(v);
      }
    }
  }
}

// ---------------------------------------------------------------------- K3
// 128 blocks x 576 threads (8 compute waves + 1 store wave), active iff
// bid%8<4 (64 roles). r=bid%8, c=bid>>3. 96 KB dynamic LDS -> 1 block/CU.
__global__ __launch_bounds__(576, 1) void k_recur(uint8_t* ws,
                                                  const int* __restrict__ vlen,
                                                  float* __restrict__ out) {
  int bid = blockIdx.x;
  if ((bid & 7) >= 4) return;
  int r = bid & 7, c = bid >> 3;

  extern __shared__ uint8_t smem[];
  uint8_t* h_lds   = smem;                     // [16][512] bf16 perm, 16384 B
  float*   tmp     = (float*)(smem + 16384);   // [16][132] f32, 8448 B
  uint8_t* g_lds   = smem + 24832;             // 2 x [16][128cols] bf16, 8192 B
  float*   pub_lds = (float*)(smem + 33024);   // 2 x 512 f32, 4096 B
  float*   c_lds   = (float*)(smem + 37120);   // 2 x 512 f32, 4096 B

  int tid = threadIdx.x;
  int lane = tid & 63, wave = tid >> 6;

  const uint8_t* Gp = ws + G_OFF;
  uint8_t* hbuf = ws + HBUF_OFF;
  uint32_t* dist = (uint32_t*)(ws + DIST_OFF + (size_t)r * 64);

  float* outH  = out;
  float* outLH = out + 8388608;
  float* outLC = out + 8421376;

  // ---- per-role constants
  bf16x8 Bfrag[16];                  // compute waves only (live regs there)
  int gb = tid >> 5, d = tid & 31;   // compute: gate mapping (batch gb, dim d)
  int gbatch = r * 16 + gb;
  int hb_b = 2 * wave + (lane >> 5); // compute: poll batch row
  int w0 = lane & 31;                // compute: poll 64B slice
  float cr = 0.0f;
  uint32_t pubw_prev = 0;
  bool fb = false;

  int b8 = lane >> 2, seg = lane & 3;            // store wave mapping
  int w8b = r * 16 + b8;
  int w8vl = 0;
  uint4 gr0, gr1, gr2, gr3;                      // store wave G staging regs

  if (wave < 8) {
    int cc = c * 128 + wave * 16 + (lane & 15);
    const uint8_t* wb = ws + WHR_OFF + (size_t)cc * 1024 + ((lane >> 4) << 4);
#pragma unroll
    for (int kk = 0; kk < 16; ++kk)
      Bfrag[kk] = *(const bf16x8*)(wb + kk * 64);
  } else {
    w8vl = vlen[w8b];
    // preload G(0) -> g_lds[0], issue G(1) -> regs
    const uint8_t* gp0 = Gp + (size_t)w8b * 4096 + (size_t)c * 256 + (size_t)seg * 64;
    uint4 a0 = *(const uint4*)(gp0);
    uint4 a1 = *(const uint4*)(gp0 + 16);
    uint4 a2 = *(const uint4*)(gp0 + 32);
    uint4 a3 = *(const uint4*)(gp0 + 48);
    uint8_t* gl = g_lds + b8 * 256 + seg * 64;
    *(uint4*)(gl)      = a0;
    *(uint4*)(gl + 16) = a1;
    *(uint4*)(gl + 32) = a2;
    *(uint4*)(gl + 48) = a3;
    const uint8_t* gp1 = gp0 + 262144;           // t=1
    gr0 = *(const uint4*)(gp1);
    gr1 = *(const uint4*)(gp1 + 16);
    gr2 = *(const uint4*)(gp1 + 32);
    gr3 = *(const uint4*)(gp1 + 48);
  }

  __syncthreads();   // startup only

  for (int t = 0; t < 256; ++t) {
    uint8_t* mybuf = hbuf + (size_t)(t & 1) * 131072;   // holds h_t
    if (wave < 8) {
      uint32_t* mypub = (uint32_t*)(mybuf + (size_t)gbatch * 2048 +
                                    (size_t)(c * 32 + d) * 4);
      // ---- poll tagged h_t (pure L2 traffic)
      u32x4 x0, x1, x2, x3;
      {
        const uint8_t* hb = mybuf + (size_t)r * 32768 +
                            (size_t)hb_b * 2048 + (size_t)w0 * 64;
        uint32_t expect = (uint32_t)((t >> 1) & 1);
        int passes = 0;
        for (;;) {
          if (!fb) {
            asm volatile(
              "global_load_dwordx4 %0, %4, off sc0\n\t"
              "global_load_dwordx4 %1, %5, off sc0\n\t"
              "global_load_dwordx4 %2, %6, off sc0\n\t"
              "global_load_dwordx4 %3, %7, off sc0\n\t"
              "s_waitcnt vmcnt(0)"
              : "=v"(x0), "=v"(x1), "=v"(x2), "=v"(x3)
              : "v"(hb), "v"(hb + 16), "v"(hb + 32), "v"(hb + 48)
              : "memory");
            __builtin_amdgcn_sched_barrier(0);
          } else {
            uint64_t y[8];
#pragma unroll
            for (int i = 0; i < 8; ++i)
              y[i] = __hip_atomic_load((const uint64_t*)(hb + i * 8),
                                       __ATOMIC_RELAXED, __HIP_MEMORY_SCOPE_AGENT);
            x0 = u32x4{(uint32_t)y[0], (uint32_t)(y[0] >> 32), (uint32_t)y[1], (uint32_t)(y[1] >> 32)};
            x1 = u32x4{(uint32_t)y[2], (uint32_t)(y[2] >> 32), (uint32_t)y[3], (uint32_t)(y[3] >> 32)};
            x2 = u32x4{(uint32_t)y[4], (uint32_t)(y[4] >> 32), (uint32_t)y[5], (uint32_t)(y[5] >> 32)};
            x3 = u32x4{(uint32_t)y[6], (uint32_t)(y[6] >> 32), (uint32_t)y[7], (uint32_t)(y[7] >> 32)};
          }
          uint32_t bad = 0;
#pragma unroll
          for (int e = 0; e < 4; ++e)
            bad |= (x0[e] ^ expect) | (x1[e] ^ expect) |
                   (x2[e] ^ expect) | (x3[e] ^ expect);
          if (__ballot((bad & 1u) != 0u) == 0ULL) break;
          ++passes;
          if (passes == 64 && !fb) {     // slow: check distress (off happy path)
            uint32_t dv = __hip_atomic_load(dist, __ATOMIC_RELAXED,
                                            __HIP_MEMORY_SCOPE_AGENT);
            if (__ballot(dv != 0) != 0ULL) {
              fb = true;
              __hip_atomic_store(mypub, pubw_prev, __ATOMIC_RELAXED,
                                 __HIP_MEMORY_SCOPE_AGENT);
            }
          }
          if (passes > 1024) {           // stuck: degrade, never hang
            passes = 512;
            if (!fb) {
              fb = true;
              __hip_atomic_store(dist, 1u, __ATOMIC_RELAXED,
                                 __HIP_MEMORY_SCOPE_AGENT);
            }
            __hip_atomic_store(mypub, pubw_prev, __ATOMIC_RELAXED,
                               __HIP_MEMORY_SCOPE_AGENT);
          }
        }
      }
      // ---- cvt f32->bf16, write permuted h_lds (R9-verified layout)
      {
        uint4 v0, v1;
        v0.x = pk2(x0[0], x0[1]); v0.y = pk2(x0[2], x0[3]);
        v0.z = pk2(x1[0], x1[1]); v0.w = pk2(x1[2], x1[3]);
        v1.x = pk2(x2[0], x2[1]); v1.y = pk2(x2[2], x2[3]);
        v1.z = pk2(x3[0], x3[1]); v1.w = pk2(x3[2], x3[3]);
        int s = hb_b & 7;
        int c0 = (2 * w0) ^ (w0 >> 2) ^ s;
        int c1 = c0 ^ 1;
        *(uint4*)(h_lds + hb_b * 1024 + c0 * 16) = v0;
        *(uint4*)(h_lds + hb_b * 1024 + c1 * 16) = v1;
      }
    } else {
      // ---- store wave: publish G(t+1) to LDS, drain outputs for t-1
      asm volatile("s_waitcnt vmcnt(0)" ::: "memory");   // G(t+1) regs landed
      __builtin_amdgcn_sched_barrier(0);
      {
        uint8_t* gl = g_lds + ((t + 1) & 1) * 4096 + b8 * 256 + seg * 64;
        *(uint4*)(gl)      = gr0;
        *(uint4*)(gl + 16) = gr1;
        *(uint4*)(gl + 32) = gr2;
        *(uint4*)(gl + 48) = gr3;
      }
      if (t > 0) {
        const float* pl = pub_lds + ((t + 1) & 1) * 512 + b8 * 32 + seg * 8;
        float4 h0 = *(const float4*)pl;
        float4 h1 = *(const float4*)(pl + 4);
        float* oh = outH + ((size_t)w8b * 256 + (size_t)(t - 1)) * 512 +
                    (size_t)(c * 32 + seg * 8);
        *(float4*)oh = h0;
        *(float4*)(oh + 4) = h1;
        if (t - 1 == w8vl - 1) {
          const float* cl = c_lds + ((t + 1) & 1) * 512 + b8 * 32 + seg * 8;
          float4 cv0 = *(const float4*)cl;
          float4 cv1 = *(const float4*)(cl + 4);
          size_t lb = (size_t)w8b * 512 + (size_t)(c * 32 + seg * 8);
          *(float4*)(outLH + lb) = h0;
          *(float4*)(outLH + lb + 4) = h1;
          *(float4*)(outLC + lb) = cv0;
          *(float4*)(outLC + lb + 4) = cv1;
        }
      }
      {  // issue G(t+2) loads (full step to land; wrap harmless, never read)
        const uint8_t* gp = Gp + (size_t)(((t + 2) & 255) * 64 + w8b) * 4096 +
                            (size_t)c * 256 + (size_t)seg * 64;
        gr0 = *(const uint4*)(gp);
        gr1 = *(const uint4*)(gp + 16);
        gr2 = *(const uint4*)(gp + 32);
        gr3 = *(const uint4*)(gp + 48);
      }
    }
    BAR_LDS();                                     // B1

    if (wave < 8) {
      // ---- MFMA: tmp(16 x wave's 16 cols) = h(16x512) @ Wh_regs
      f32x4 acc0 = f32x4{0.f, 0.f, 0.f, 0.f}, acc1 = acc0;
      {
        int lrow = lane & 15;
        int g = lane >> 4;
        int gs = (g ^ (lrow & 7)) * 16;
#pragma unroll
        for (int kk = 0; kk < 16; kk += 2) {
          int k0c = ((kk * 4) ^ (kk >> 1)) * 16;
          int k1c = (((kk + 1) * 4) ^ ((kk + 1) >> 1)) * 16;
          bf16x8 a0 = *(const bf16x8*)(h_lds + lrow * 1024 + (k0c ^ gs));
          bf16x8 a1 = *(const bf16x8*)(h_lds + lrow * 1024 + (k1c ^ gs));
          acc0 = __builtin_amdgcn_mfma_f32_16x16x32_bf16(a0, Bfrag[kk], acc0, 0, 0, 0);
          acc1 = __builtin_amdgcn_mfma_f32_16x16x32_bf16(a1, Bfrag[kk + 1], acc1, 0, 0, 0);
        }
      }
      {
        int colb = wave * 16 + (lane & 15);
        int rowd = (lane >> 4) << 2;
#pragma unroll
        for (int q = 0; q < 4; ++q)
          tmp[(rowd + q) * 132 + colb] = acc0[q] + acc1[q];
      }
    }
    BAR_LDS();                                     // B2

    if (wave < 8) {
      // ---- gates (G from LDS; zero HBM ops on compute waves)
      float hval, cval;
      {
        uint64_t gx = *(const uint64_t*)(g_lds + (t & 1) * 4096 + gb * 256 + d * 8);
        int tb = gb * 132 + d;
        float ip = tmp[tb]      + bf2f((unsigned short)(gx & 0xFFFF));
        float fp = tmp[tb + 32] + bf2f((unsigned short)((gx >> 16) & 0xFFFF));
        float op = tmp[tb + 64] + bf2f((unsigned short)((gx >> 32) & 0xFFFF));
        float gp = tmp[tb + 96] + bf2f((unsigned short)((gx >> 48) & 0xFFFF));
        float ig = fsigmoid(ip), fg = fsigmoid(fp), og = fsigmoid(op);
        float gt = ftanh(gp);
        cval = fg * cr + ig * gt;
        cr = cval;
        hval = og * ftanh(cval);
      }
      // ---- publish h_{t+1} (plain, L2) + immediate flush (L2 ack only)
      {
        uint32_t wtag = (uint32_t)(((t + 1) >> 1) & 1);
        uint32_t pubw = (f2u(hval) & ~1u) | wtag;
        uint32_t* pub = (uint32_t*)(hbuf + (size_t)((t + 1) & 1) * 131072 +
                                    (size_t)gbatch * 2048 + (size_t)(c * 32 + d) * 4);
        asm volatile("global_store_dword %0, %1, off" :: "v"(pub), "v"(pubw) : "memory");
        if (fb)
          __hip_atomic_store(pub, pubw, __ATOMIC_RELAXED, __HIP_MEMORY_SCOPE_AGENT);
        asm volatile("s_waitcnt vmcnt(0)" ::: "memory");
        __builtin_amdgcn_sched_barrier(0);
        pubw_prev = pubw;
      }
      // ---- stage outputs to LDS for the store wave
      pub_lds[(t & 1) * 512 + tid] = hval;
      c_lds[(t & 1) * 512 + tid] = cval;
    }
    BAR_LDS();                                     // B3
  }
  // ---- epilogue (store wave): row 255 outputs
  if (wave == 8) {
    const float* pl = pub_lds + 512 + b8 * 32 + seg * 8;   // buf (255&1)=1
    float4 h0 = *(const float4*)pl;
    float4 h1 = *(const float4*)(pl + 4);
    float* oh = outH + ((size_t)w8b * 256 + 255) * 512 + (size_t)(c * 32 + seg * 8);
    *(float4*)oh = h0;
    *(float4*)(oh + 4) = h1;
    if (w8vl == 256) {
      const float* cl = c_lds + 512 + b8 * 32 + seg * 8;
      float4 cv0 = *(const float4*)cl;
      float4 cv1 = *(const float4*)(cl + 4);
      size_t lb = (size_t)w8b * 512 + (size_t)(c * 32 + seg * 8);
      *(float4*)(outLH + lb) = h0;
      *(float4*)(outLH + lb + 4) = h1;
      *(float4*)(outLC + lb) = cv0;
      *(float4*)(outLC + lb + 4) = cv1;
    }
  }
}

// ---------------------------------------------------------------------------
extern "C" void kernel_launch(void* const* d_in, const int* in_sizes, int n_in,
                              void* d_out, int out_size, void* d_ws, size_t ws_size,
                              hipStream_t stream) {
  const int*   loc     = (const int*)d_in[0];
  const int*   tdu     = (const int*)d_in[1];
  const int*   tdl     = (const int*)d_in[2];
  const int*   sdu     = (const int*)d_in[3];
  const int*   sdl     = (const int*)d_in[4];
  const int*   vlen    = (const int*)d_in[5];
  const float* loc_emb = (const float*)d_in[6];
  const float* tup     = (const float*)d_in[7];
  const float* tlo     = (const float*)d_in[8];
  const float* sup     = (const float*)d_in[9];
  const float* slo     = (const float*)d_in[10];
  const float* Wt      = (const float*)d_in[11];
  const float* Ws      = (const float*)d_in[12];
  const float* Wi      = (const float*)d_in[13];
  const float* bi      = (const float*)d_in[14];
  const float* Wh      = (const float*)d_in[15];
  uint8_t* ws = (uint8_t*)d_ws;
  float* out = (float*)d_out;

  if (ws_size < WS_NEED) return;  // need ~120.2 MiB scratch

  (void)hipFuncSetAttribute((const void*)k_recur,
                            hipFuncAttributeMaxDynamicSharedMemorySize, 98304);

  k_prep  <<<2113, 256, 0, stream>>>(Wi, Wt, Ws, Wh, ws);
  k_gather<<<16384, 192, 0, stream>>>(loc, tdu, tdl, sdu, sdl,
                                      loc_emb, tup, tlo, sup, slo, ws);
  k_gemm  <<<2048, 256, 0, stream>>>(ws, bi);
  k_recur <<<128, 576, 98304, stream>>>(ws, vlen, out);
}